// Round 1
// baseline (726.246 us; speedup 1.0000x reference)
//
#include <hip/hip_runtime.h>

#define PIX 262144   // 512*512
#define CCH 64
#define KK  16
#define ACCN (16 + 1024 + 16 + 1024)  // counts, psum, sumsq, G

// ---------------- K1: zero accumulators, pack masks, compute y = rsqrt(||X2col||^2) ----
__global__ __launch_bounds__(256) void k1_pack_norm(
        const int* __restrict__ masks, const float* __restrict__ x2,
        unsigned short* __restrict__ packed, float* __restrict__ yv,
        float* __restrict__ accz) {
    if (blockIdx.x == 0) {
        for (int i = threadIdx.x; i < ACCN; i += 256) accz[i] = 0.f;
    }
    int t = blockIdx.x * 256 + threadIdx.x;   // 512 blocks * 256 thr * 2 px = PIX
    int p = t * 2;
    unsigned m0 = 0, m1 = 0;
    #pragma unroll
    for (int k = 0; k < KK; ++k) {
        int2 mv = *(const int2*)(masks + (size_t)k * PIX + p);
        m0 |= (unsigned)(mv.x == 1) << k;
        m1 |= (unsigned)(mv.y == 1) << k;
    }
    packed[p]     = (unsigned short)m0;
    packed[p + 1] = (unsigned short)m1;
    float s0 = 0.f, s1 = 0.f;
    #pragma unroll
    for (int c = 0; c < CCH; ++c) {
        float2 v = *(const float2*)(x2 + (size_t)c * PIX + p);
        s0 = fmaf(v.x, v.x, s0);
        s1 = fmaf(v.y, v.y, s1);
    }
    yv[p]     = (s0 > 0.f) ? rsqrtf(s0) : 0.f;
    yv[p + 1] = (s1 > 0.f) ? rsqrtf(s1) : 0.f;
}

__device__ __forceinline__ float wred64(float v) {
    #pragma unroll
    for (int o = 32; o > 0; o >>= 1) v += __shfl_xor(v, o, 64);
    return v;
}

// ---------------- K2: masked channel sums -------------------------------------------
// blocks [0,512): type A -> psum[k][c] (X1), sumsq[k], counts[k]
// blocks [512,1024): type B -> G[k][c] (y * X2)
__global__ __launch_bounds__(256) void k2_accum(
        const float* __restrict__ x1, const float* __restrict__ x2,
        const unsigned short* __restrict__ packed, const float* __restrict__ yv,
        float* __restrict__ counts, float* __restrict__ psum,
        float* __restrict__ sumsq, float* __restrict__ G) {
    const int NS = 32;                 // slices per type
    int b = blockIdx.x;
    bool typeB = (b >= 16 * NS);
    if (typeB) b -= 16 * NS;
    int g  = b & 15;                   // channel group (4 channels)
    int sl = b >> 4;                   // slice 0..31
    int base = sl * (PIX / NS);        // 8192-px slice
    int tid = threadIdx.x;
    bool doCnt = (!typeB) && (g == 0);

    float acc[4][16];
    float accS[16];
    float accC[16];
    #pragma unroll
    for (int c = 0; c < 4; ++c)
        #pragma unroll
        for (int k = 0; k < 16; ++k) acc[c][k] = 0.f;
    #pragma unroll
    for (int k = 0; k < 16; ++k) { accS[k] = 0.f; accC[k] = 0.f; }

    const float* Xg = (typeB ? x2 : x1) + (size_t)(g * 4) * PIX;

    for (int pk = 0; pk < 8; ++pk) {
        int px = base + ((pk << 8) + tid) * 4;   // 4-px packet
        float4 xv[4];
        #pragma unroll
        for (int c = 0; c < 4; ++c) xv[c] = *(const float4*)(Xg + (size_t)c * PIX + px);
        ushort4 mv = *(const ushort4*)(packed + px);
        float4 yv4 = make_float4(0.f, 0.f, 0.f, 0.f);
        if (typeB) yv4 = *(const float4*)(yv + px);

        #pragma unroll
        for (int q = 0; q < 4; ++q) {
            unsigned m = (q == 0) ? mv.x : (q == 1) ? mv.y : (q == 2) ? mv.z : mv.w;
            float x0 = (q == 0) ? xv[0].x : (q == 1) ? xv[0].y : (q == 2) ? xv[0].z : xv[0].w;
            float x1e= (q == 0) ? xv[1].x : (q == 1) ? xv[1].y : (q == 2) ? xv[1].z : xv[1].w;
            float x2e= (q == 0) ? xv[2].x : (q == 1) ? xv[2].y : (q == 2) ? xv[2].z : xv[2].w;
            float x3 = (q == 0) ? xv[3].x : (q == 1) ? xv[3].y : (q == 2) ? xv[3].z : xv[3].w;
            if (typeB) {
                float w = (q == 0) ? yv4.x : (q == 1) ? yv4.y : (q == 2) ? yv4.z : yv4.w;
                x0 *= w; x1e *= w; x2e *= w; x3 *= w;
                #pragma unroll
                for (int k = 0; k < 16; ++k) {
                    float f = (float)((m >> k) & 1u);
                    acc[0][k] = fmaf(f, x0,  acc[0][k]);
                    acc[1][k] = fmaf(f, x1e, acc[1][k]);
                    acc[2][k] = fmaf(f, x2e, acc[2][k]);
                    acc[3][k] = fmaf(f, x3,  acc[3][k]);
                }
            } else {
                float ss = x0 * x0;
                ss = fmaf(x1e, x1e, ss);
                ss = fmaf(x2e, x2e, ss);
                ss = fmaf(x3,  x3,  ss);
                #pragma unroll
                for (int k = 0; k < 16; ++k) {
                    float f = (float)((m >> k) & 1u);
                    acc[0][k] = fmaf(f, x0,  acc[0][k]);
                    acc[1][k] = fmaf(f, x1e, acc[1][k]);
                    acc[2][k] = fmaf(f, x2e, acc[2][k]);
                    acc[3][k] = fmaf(f, x3,  acc[3][k]);
                    accS[k]   = fmaf(f, ss,  accS[k]);
                    if (doCnt) accC[k] += f;
                }
            }
        }
    }

    int lane = threadIdx.x & 63;
    float* dst = typeB ? G : psum;
    #pragma unroll
    for (int k = 0; k < 16; ++k) {
        #pragma unroll
        for (int c = 0; c < 4; ++c) {
            float v = wred64(acc[c][k]);
            if (lane == 0) atomicAdd(dst + k * 64 + g * 4 + c, v);
        }
        if (!typeB) {
            float v = wred64(accS[k]);
            if (lane == 0) atomicAdd(sumsq + k, v);
            if (doCnt) {
                float v2 = wred64(accC[k]);
                if (lane == 0) atomicAdd(counts + k, v2);
            }
        }
    }
}

// ---------------- K3: finalize ------------------------------------------------------
__global__ __launch_bounds__(256) void k3_finalize(
        const int* __restrict__ labels, const float* __restrict__ counts,
        const float* __restrict__ psum, const float* __restrict__ sumsq,
        const float* __restrict__ G, float* __restrict__ out) {
    __shared__ float meansS[16][64];
    __shared__ float Gs[16][64];
    __shared__ float cntS[16], rawcS[16], nmS[16], stdS[16];
    __shared__ float simS[16][16];
    int t = threadIdx.x;

    if (t < 16) {
        float c0 = counts[t];
        rawcS[t] = c0;
        cntS[t] = fmaxf(c0, 1.f);
    }
    __syncthreads();
    for (int i = t; i < 1024; i += 256) {
        int k = i >> 6, c = i & 63;
        meansS[k][c] = psum[i] / cntS[k];
        Gs[k][c] = G[i];
    }
    __syncthreads();
    if (t < 16) {
        float s = 0.f, sa = 0.f;
        for (int c = 0; c < 64; ++c) {
            s = fmaf(meansS[t][c], meansS[t][c], s);
            sa += psum[t * 64 + c];
        }
        nmS[t] = sqrtf(s);
        float ne = rawcS[t] * 64.f;
        float ma = sa / fmaxf(ne, 1.f);
        float var = (sumsq[t] - ne * ma * ma) / fmaxf(ne - 1.f, 1.f);
        stdS[t] = sqrtf(fmaxf(var, 0.f));
    }
    __syncthreads();
    {
        int i = t >> 4, j = t & 15;
        float d = 0.f;
        for (int c = 0; c < 64; ++c) d = fmaf(meansS[i][c], Gs[j][c], d);
        simS[i][j] = d / (fmaxf(nmS[i], 1e-30f) * cntS[j]);
    }
    __syncthreads();
    if (t == 0) {
        int lab[16];
        for (int k = 0; k < 16; ++k) lab[k] = labels[k];
        float cc[11], inst[11], csim[11], cstd[11];
        for (int l = 0; l < 11; ++l) { cc[l]=0.f; inst[l]=0.f; csim[l]=0.f; cstd[l]=0.f; }
        for (int k = 0; k < 16; ++k) cc[lab[k]] += 1.f;
        for (int k = 0; k < 16; ++k) inst[lab[k]] += simS[k][k];
        for (int i = 0; i < 16; ++i) {
            float row = 0.f;
            for (int j = 0; j < 16; ++j)
                if (j != i && lab[j] == lab[i]) row += simS[i][j];
            csim[lab[i]] += row;
        }
        for (int k = 0; k < 16; ++k) cstd[lab[k]] += stdS[k];
        float nb[3];
        for (int bq = 0; bq < 3; ++bq) {
            float c = 0.f, s = 0.f;
            for (int i = 0; i < 16; ++i) {
                for (int j = 0; j < 16; ++j) {
                    if (lab[i] == lab[j]) continue;
                    bool gi, gj;
                    if (bq == 0)      { gi = lab[i] >= 1 && lab[i] <= 8;  gj = lab[j] >= 1 && lab[j] <= 8; }
                    else if (bq == 1) { gi = lab[i] >= 3 && lab[i] <= 10; gj = lab[j] >= 3 && lab[j] <= 10; }
                    else { gi = (lab[i] >= 1 && lab[i] <= 2) || (lab[i] >= 9 && lab[i] <= 10);
                           gj = (lab[j] >= 1 && lab[j] <= 2) || (lab[j] >= 9 && lab[j] <= 10); }
                    if (gi && gj) { c += 1.f; s += simS[i][j]; }
                }
            }
            nb[bq] = (c > 1.f) ? (s / c) : s;
        }
        for (int l = 0; l < 11; ++l) {
            if (cc[l] > 1.f) {
                inst[l] /= fmaxf(cc[l], 1.f);
                csim[l] /= fmaxf(cc[l] * (cc[l] - 1.f), 1.f);
                cstd[l] /= cc[l];
            }
            out[l]      = inst[l];
            out[11 + l] = csim[l];
            out[25 + l] = cstd[l];
        }
        out[22] = nb[0];
        out[23] = nb[1];
        out[24] = nb[2];
    }
}

extern "C" void kernel_launch(void* const* d_in, const int* in_sizes, int n_in,
                              void* d_out, int out_size, void* d_ws, size_t ws_size,
                              hipStream_t stream) {
    const float* x1     = (const float*)d_in[0];
    const float* x2     = (const float*)d_in[1];
    const int*   masks  = (const int*)d_in[2];
    const int*   labels = (const int*)d_in[3];
    float* out = (float*)d_out;

    char* ws = (char*)d_ws;
    unsigned short* packed = (unsigned short*)ws;                  // PIX*2 bytes
    float* yv  = (float*)(ws + (size_t)PIX * 2);                   // PIX*4 bytes
    float* acc = (float*)(ws + (size_t)PIX * 2 + (size_t)PIX * 4); // ACCN floats
    float* counts = acc;
    float* psum   = acc + 16;
    float* sumsq  = acc + 16 + 1024;
    float* Gacc   = acc + 16 + 1024 + 16;

    k1_pack_norm<<<512, 256, 0, stream>>>(masks, x2, packed, yv, acc);
    k2_accum<<<1024, 256, 0, stream>>>(x1, x2, packed, yv, counts, psum, sumsq, Gacc);
    k3_finalize<<<1, 256, 0, stream>>>(labels, counts, psum, sumsq, Gacc, out);
}

// Round 2
// 377.907 us; speedup vs baseline: 1.9218x; 1.9218x over previous
//
#include <hip/hip_runtime.h>

#define PIX 262144   // 512*512
#define CCH 64
#define KK  16
// acc region layout (floats): counts[16*32] | sumsq[16*32] | psum[1024] | G[1024]
#define ACCN (512 + 512 + 1024 + 1024)

// ---------------- K1: pack masks, y = rsqrt(||X2col||^2), counts via ballot ----------
__global__ __launch_bounds__(256, 4) void k1_pack_norm(
        const int* __restrict__ masks, const float* __restrict__ x2,
        unsigned short* __restrict__ packed, float* __restrict__ yv,
        float* __restrict__ counts) {
    int t = blockIdx.x * 256 + threadIdx.x;   // 512 blocks * 256 thr * 2 px = PIX
    int p = t * 2;
    unsigned m0 = 0, m1 = 0;
    #pragma unroll
    for (int k = 0; k < KK; ++k) {
        int2 mv = *(const int2*)(masks + (size_t)k * PIX + p);
        m0 |= (unsigned)(mv.x == 1) << k;
        m1 |= (unsigned)(mv.y == 1) << k;
    }
    packed[p]     = (unsigned short)m0;
    packed[p + 1] = (unsigned short)m1;

    float s0 = 0.f, s1 = 0.f;
    #pragma unroll 8
    for (int c = 0; c < CCH; ++c) {
        float2 v = *(const float2*)(x2 + (size_t)c * PIX + p);
        s0 = fmaf(v.x, v.x, s0);
        s1 = fmaf(v.y, v.y, s1);
    }
    yv[p]     = (s0 > 0.f) ? rsqrtf(s0) : 0.f;
    yv[p + 1] = (s1 > 0.f) ? rsqrtf(s1) : 0.f;

    // counts[k] += popcount over this block's pixels
    __shared__ float wc[4][16];
    int wid = threadIdx.x >> 6, lane = threadIdx.x & 63;
    #pragma unroll
    for (int k = 0; k < KK; ++k) {
        unsigned long long b0 = __ballot((m0 >> k) & 1u);
        unsigned long long b1 = __ballot((m1 >> k) & 1u);
        if (lane == 0) wc[wid][k] = (float)(__popcll(b0) + __popcll(b1));
    }
    __syncthreads();
    if (threadIdx.x < 16) {
        int k = threadIdx.x;
        float s = wc[0][k] + wc[1][k] + wc[2][k] + wc[3][k];
        atomicAdd(counts + k * 32, s);
    }
}

__device__ __forceinline__ float wred64(float v) {
    #pragma unroll
    for (int o = 32; o > 0; o >>= 1) v += __shfl_xor(v, o, 64);
    return v;
}

// ---------------- K2: masked channel sums -------------------------------------------
// blocks [0,1024): type A -> psum[k][c] (X1), sumsq[k]
// blocks [1024,2048): type B -> G[k][c] (y * X2)
__global__ __launch_bounds__(256, 3) void k2_accum(
        const float* __restrict__ x1, const float* __restrict__ x2,
        const unsigned short* __restrict__ packed, const float* __restrict__ yv,
        float* __restrict__ psum, float* __restrict__ sumsq, float* __restrict__ G) {
    const int NS = 64;                 // slices per type
    int b = blockIdx.x;
    bool typeB = (b >= 16 * NS);
    if (typeB) b -= 16 * NS;
    int g  = b & 15;                   // channel group (4 channels)
    int sl = b >> 4;                   // slice 0..63
    int base = sl * (PIX / NS);        // 4096-px slice
    int tid = threadIdx.x;

    float acc[4][16];
    float accS[16];
    #pragma unroll
    for (int c = 0; c < 4; ++c)
        #pragma unroll
        for (int k = 0; k < 16; ++k) acc[c][k] = 0.f;
    #pragma unroll
    for (int k = 0; k < 16; ++k) accS[k] = 0.f;

    const float* Xg = (typeB ? x2 : x1) + (size_t)(g * 4) * PIX;

    for (int pk = 0; pk < 4; ++pk) {
        int px = base + ((pk << 8) + tid) * 4;   // 4-px packet
        float4 xv[4];
        #pragma unroll
        for (int c = 0; c < 4; ++c) xv[c] = *(const float4*)(Xg + (size_t)c * PIX + px);
        ushort4 mv = *(const ushort4*)(packed + px);
        float4 yv4 = make_float4(0.f, 0.f, 0.f, 0.f);
        if (typeB) yv4 = *(const float4*)(yv + px);

        #pragma unroll
        for (int q = 0; q < 4; ++q) {
            unsigned m = (q == 0) ? mv.x : (q == 1) ? mv.y : (q == 2) ? mv.z : mv.w;
            float x0 = (q == 0) ? xv[0].x : (q == 1) ? xv[0].y : (q == 2) ? xv[0].z : xv[0].w;
            float x1e= (q == 0) ? xv[1].x : (q == 1) ? xv[1].y : (q == 2) ? xv[1].z : xv[1].w;
            float x2e= (q == 0) ? xv[2].x : (q == 1) ? xv[2].y : (q == 2) ? xv[2].z : xv[2].w;
            float x3 = (q == 0) ? xv[3].x : (q == 1) ? xv[3].y : (q == 2) ? xv[3].z : xv[3].w;
            if (typeB) {
                float w = (q == 0) ? yv4.x : (q == 1) ? yv4.y : (q == 2) ? yv4.z : yv4.w;
                x0 *= w; x1e *= w; x2e *= w; x3 *= w;
                #pragma unroll
                for (int k = 0; k < 16; ++k) {
                    float f = (float)((m >> k) & 1u);
                    acc[0][k] = fmaf(f, x0,  acc[0][k]);
                    acc[1][k] = fmaf(f, x1e, acc[1][k]);
                    acc[2][k] = fmaf(f, x2e, acc[2][k]);
                    acc[3][k] = fmaf(f, x3,  acc[3][k]);
                }
            } else {
                float ss = x0 * x0;
                ss = fmaf(x1e, x1e, ss);
                ss = fmaf(x2e, x2e, ss);
                ss = fmaf(x3,  x3,  ss);
                #pragma unroll
                for (int k = 0; k < 16; ++k) {
                    float f = (float)((m >> k) & 1u);
                    acc[0][k] = fmaf(f, x0,  acc[0][k]);
                    acc[1][k] = fmaf(f, x1e, acc[1][k]);
                    acc[2][k] = fmaf(f, x2e, acc[2][k]);
                    acc[3][k] = fmaf(f, x3,  acc[3][k]);
                    accS[k]   = fmaf(f, ss,  accS[k]);
                }
            }
        }
    }

    // block-level reduction: wave shuffle -> LDS -> one atomic per value
    __shared__ float red[16][4][4];   // [k][c][wave]
    __shared__ float redS[16][4];     // [k][wave]
    int wid = tid >> 6, lane = tid & 63;
    #pragma unroll
    for (int k = 0; k < 16; ++k) {
        #pragma unroll
        for (int c = 0; c < 4; ++c) {
            float v = wred64(acc[c][k]);
            if (lane == 0) red[k][c][wid] = v;
        }
        if (!typeB) {
            float v = wred64(accS[k]);
            if (lane == 0) redS[k][wid] = v;
        }
    }
    __syncthreads();
    float* dst = typeB ? G : psum;
    if (tid < 64) {
        int k = tid >> 2, c = tid & 3;
        float s = red[k][c][0] + red[k][c][1] + red[k][c][2] + red[k][c][3];
        atomicAdd(dst + k * 64 + g * 4 + c, s);
    }
    if (!typeB && tid < 16) {
        float s = redS[tid][0] + redS[tid][1] + redS[tid][2] + redS[tid][3];
        atomicAdd(sumsq + tid * 32, s);
    }
}

// ---------------- K3: finalize ------------------------------------------------------
__global__ __launch_bounds__(256) void k3_finalize(
        const int* __restrict__ labels, const float* __restrict__ counts,
        const float* __restrict__ psum, const float* __restrict__ sumsq,
        const float* __restrict__ G, float* __restrict__ out) {
    __shared__ float meansS[16][64];
    __shared__ float Gs[16][64];
    __shared__ float cntS[16], rawcS[16], nmS[16], stdS[16];
    __shared__ float simS[16][16];
    int t = threadIdx.x;

    if (t < 16) {
        float c0 = counts[t * 32];
        rawcS[t] = c0;
        cntS[t] = fmaxf(c0, 1.f);
    }
    __syncthreads();
    for (int i = t; i < 1024; i += 256) {
        int k = i >> 6, c = i & 63;
        meansS[k][c] = psum[i] / cntS[k];
        Gs[k][c] = G[i];
    }
    __syncthreads();
    if (t < 16) {
        float s = 0.f, sa = 0.f;
        for (int c = 0; c < 64; ++c) {
            s = fmaf(meansS[t][c], meansS[t][c], s);
            sa += psum[t * 64 + c];
        }
        nmS[t] = sqrtf(s);
        float ne = rawcS[t] * 64.f;
        float ma = sa / fmaxf(ne, 1.f);
        float var = (sumsq[t * 32] - ne * ma * ma) / fmaxf(ne - 1.f, 1.f);
        stdS[t] = sqrtf(fmaxf(var, 0.f));
    }
    __syncthreads();
    {
        int i = t >> 4, j = t & 15;
        float d = 0.f;
        for (int c = 0; c < 64; ++c) d = fmaf(meansS[i][c], Gs[j][c], d);
        simS[i][j] = d / (fmaxf(nmS[i], 1e-30f) * cntS[j]);
    }
    __syncthreads();
    if (t == 0) {
        int lab[16];
        for (int k = 0; k < 16; ++k) lab[k] = labels[k];
        float cc[11], inst[11], csim[11], cstd[11];
        for (int l = 0; l < 11; ++l) { cc[l]=0.f; inst[l]=0.f; csim[l]=0.f; cstd[l]=0.f; }
        for (int k = 0; k < 16; ++k) cc[lab[k]] += 1.f;
        for (int k = 0; k < 16; ++k) inst[lab[k]] += simS[k][k];
        for (int i = 0; i < 16; ++i) {
            float row = 0.f;
            for (int j = 0; j < 16; ++j)
                if (j != i && lab[j] == lab[i]) row += simS[i][j];
            csim[lab[i]] += row;
        }
        for (int k = 0; k < 16; ++k) cstd[lab[k]] += stdS[k];
        float nb[3];
        for (int bq = 0; bq < 3; ++bq) {
            float c = 0.f, s = 0.f;
            for (int i = 0; i < 16; ++i) {
                for (int j = 0; j < 16; ++j) {
                    if (lab[i] == lab[j]) continue;
                    bool gi, gj;
                    if (bq == 0)      { gi = lab[i] >= 1 && lab[i] <= 8;  gj = lab[j] >= 1 && lab[j] <= 8; }
                    else if (bq == 1) { gi = lab[i] >= 3 && lab[i] <= 10; gj = lab[j] >= 3 && lab[j] <= 10; }
                    else { gi = (lab[i] >= 1 && lab[i] <= 2) || (lab[i] >= 9 && lab[i] <= 10);
                           gj = (lab[j] >= 1 && lab[j] <= 2) || (lab[j] >= 9 && lab[j] <= 10); }
                    if (gi && gj) { c += 1.f; s += simS[i][j]; }
                }
            }
            nb[bq] = (c > 1.f) ? (s / c) : s;
        }
        for (int l = 0; l < 11; ++l) {
            if (cc[l] > 1.f) {
                inst[l] /= fmaxf(cc[l], 1.f);
                csim[l] /= fmaxf(cc[l] * (cc[l] - 1.f), 1.f);
                cstd[l] /= cc[l];
            }
            out[l]      = inst[l];
            out[11 + l] = csim[l];
            out[25 + l] = cstd[l];
        }
        out[22] = nb[0];
        out[23] = nb[1];
        out[24] = nb[2];
    }
}

extern "C" void kernel_launch(void* const* d_in, const int* in_sizes, int n_in,
                              void* d_out, int out_size, void* d_ws, size_t ws_size,
                              hipStream_t stream) {
    const float* x1     = (const float*)d_in[0];
    const float* x2     = (const float*)d_in[1];
    const int*   masks  = (const int*)d_in[2];
    const int*   labels = (const int*)d_in[3];
    float* out = (float*)d_out;

    char* ws = (char*)d_ws;
    unsigned short* packed = (unsigned short*)ws;                  // PIX*2 bytes
    float* yv  = (float*)(ws + (size_t)PIX * 2);                   // PIX*4 bytes
    float* acc = (float*)(ws + (size_t)PIX * 2 + (size_t)PIX * 4); // ACCN floats
    float* counts = acc;            // stride-32 padded, 16 entries
    float* sumsq  = acc + 512;      // stride-32 padded, 16 entries
    float* psum   = acc + 1024;     // [16][64]
    float* Gacc   = acc + 2048;     // [16][64]

    hipMemsetAsync(acc, 0, (size_t)ACCN * sizeof(float), stream);
    k1_pack_norm<<<512, 256, 0, stream>>>(masks, x2, packed, yv, counts);
    k2_accum<<<2048, 256, 0, stream>>>(x1, x2, packed, yv, psum, sumsq, Gacc);
    k3_finalize<<<1, 256, 0, stream>>>(labels, counts, psum, sumsq, Gacc, out);
}